// Round 7
// baseline (434.198 us; speedup 1.0000x reference)
//
#include <hip/hip_runtime.h>
#include <hip/hip_bf16.h>
#include <hip/hip_fp16.h>
#include <math.h>

// Problem dims (fixed by reference)
#define B_  32
#define T_  512
#define F_  4096
#define H_  128
#define G4H 512           // 4*H
#define NCLS 3            // NUM_CLASSES + 1
#define M_  (B_ * T_)     // 16384 rows
#define KSTEPS 128        // F_/32

typedef _Float16 f16x8 __attribute__((ext_vector_type(8)));
typedef _Float16 f16x4 __attribute__((ext_vector_type(4)));
typedef float    f32x4 __attribute__((ext_vector_type(4)));

// ---------------------------------------------------------------------------
// Kernel 0b: Wk [F,4H] fp32 -> btK fp16, K-MAJOR tiles with baked-in group
// swizzle: group g (8 halves) of column n stored at half-offset
//   n*32 + ((g ^ ((n>>1)&3)) << 3)
// ---------------------------------------------------------------------------
__global__ __launch_bounds__(256) void cvt_wkT(
    const float* __restrict__ Wk, _Float16* __restrict__ btK)
{
    __shared__ float ls[64][65];
    const int k0 = blockIdx.x * 64;
    const int n0 = blockIdx.y * 64;
    const int tid = threadIdx.x;

    {
        int r  = tid >> 4;
        int c4 = (tid & 15) * 4;
        #pragma unroll
        for (int p = 0; p < 4; ++p) {
            float4 v = *reinterpret_cast<const float4*>(
                &Wk[(size_t)(k0 + r + p * 16) * G4H + n0 + c4]);
            ls[r + p * 16][c4 + 0] = v.x;
            ls[r + p * 16][c4 + 1] = v.y;
            ls[r + p * 16][c4 + 2] = v.z;
            ls[r + p * 16][c4 + 3] = v.w;
        }
    }
    __syncthreads();
    {
        int rn = tid >> 2;            // n within tile 0..63
        int ck = (tid & 3) * 16;      // k within tile 0,16,32,48
        f16x8 h0, h1;
        #pragma unroll
        for (int j = 0; j < 8; ++j) {
            h0[j] = (_Float16)ls[ck + j][rn];
            h1[j] = (_Float16)ls[ck + 8 + j][rn];
        }
        const int n    = n0 + rn;
        const int kg   = k0 + ck;
        const int kblk = kg >> 5;
        const int kk   = kg & 31;           // 0 or 16
        const int g0   = kk >> 3;           // 0 or 2
        const int sw   = (n >> 1) & 3;
        _Float16* base = btK + (size_t)kblk * (512 * 32) + (size_t)n * 32;
        *reinterpret_cast<f16x8*>(base + ((g0 ^ sw) << 3))       = h0;
        *reinterpret_cast<f16x8*>(base + (((g0 + 1) ^ sw) << 3)) = h1;
    }
}

// ---------------------------------------------------------------------------
// Kernel 0c: Wr [H,4H] fp32 -> wrT [4H,H] fp16 (transpose). grid (2, 8).
// ---------------------------------------------------------------------------
__global__ __launch_bounds__(256) void cvt_wrT(
    const float* __restrict__ Wr, _Float16* __restrict__ wrT)
{
    __shared__ float ls[64][65];
    const int k0 = blockIdx.x * 64;
    const int n0 = blockIdx.y * 64;
    const int tid = threadIdx.x;
    {
        int r  = tid >> 4;
        int c4 = (tid & 15) * 4;
        #pragma unroll
        for (int p = 0; p < 4; ++p) {
            float4 v = *reinterpret_cast<const float4*>(
                &Wr[(size_t)(k0 + r + p * 16) * G4H + n0 + c4]);
            ls[r + p * 16][c4 + 0] = v.x;
            ls[r + p * 16][c4 + 1] = v.y;
            ls[r + p * 16][c4 + 2] = v.z;
            ls[r + p * 16][c4 + 3] = v.w;
        }
    }
    __syncthreads();
    {
        int rn = tid >> 2;
        int ck = (tid & 3) * 16;
        f16x8 h0, h1;
        #pragma unroll
        for (int j = 0; j < 8; ++j) {
            h0[j] = (_Float16)ls[ck + j][rn];
            h1[j] = (_Float16)ls[ck + 8 + j][rn];
        }
        _Float16* dst = &wrT[(size_t)(n0 + rn) * H_ + k0 + ck];
        *reinterpret_cast<f16x8*>(dst)     = h0;
        *reinterpret_cast<f16x8*>(dst + 8) = h1;
    }
}

// Light producer-consumer barrier: LDS-drain only, no vmcnt drain.
__device__ __forceinline__ void lds_barrier() {
    asm volatile("s_waitcnt lgkmcnt(0)" ::: "memory");
    __builtin_amdgcn_s_barrier();
    asm volatile("" ::: "memory");
}

// ---------------------------------------------------------------------------
// Kernel 1: FUSED z = f16(x) @ Wk + b.
// R22: 4 independent blocks/CU (the one lever that ever moved gemm: round0->
// R16 was 1->2 blocks/CU = 204->127us; R20/R21 resource micro-opts were null,
// all pipes <=70% => lockstep-phase-serialization bound; independent barrier
// domains per CU overlap the phases).
//  - BM=64, BN=128, 256 threads (4 waves), grid 1024, launch_bounds(256,4).
//  - B in registers (R21), A tile staged via LDS double-buffer (R16 path).
//  - z now stored PLANAR [row][gate*128+ch]: 64B-coalesced stores (the old
//    gate-interleave forced 4B-scatter with 2x write amplification).
// Same k-order / RTN cvt / MFMA fragments => z values bit-exact.
// ---------------------------------------------------------------------------
__global__ __launch_bounds__(256, 4) void gemm_fused(
    const float* __restrict__ x, const _Float16* __restrict__ btK,
    const float* __restrict__ bias, float* __restrict__ z)
{
    __shared__ __align__(16) _Float16 As[2][64 * 32];    // 8 KB

    const int tid = threadIdx.x;
    const int w   = tid >> 6;          // 0..3
    const int l   = tid & 63;
    const int fr  = l & 15;
    const int q   = l >> 4;

    // grid 1024 = 8 xcd * (32 m-tiles * 4 n-tiles); the 4 n-siblings of an
    // m-tile are adjacent on one XCD -> x re-reads hit that XCD's L2.
    const int bid   = blockIdx.x;
    const int xcd   = bid & 7;
    const int idx   = bid >> 3;        // 0..127
    const int mt    = xcd * 32 + (idx >> 2);
    const int ntile = idx & 3;
    const int m0    = mt * 64;
    const int n0    = ntile * 128;

    // x staging: thread covers rows ar and ar+32, cols hc..hc+3
    const int ar = tid >> 3;           // 0..31
    const int hc = (tid & 7) * 4;
    const int abyte = ((((hc >> 3) ^ ((ar >> 1) & 3)) << 4) | ((hc << 1) & 15));
    const float* xrow0 = x + (size_t)(m0 + ar) * F_ + hc;
    const float* xrow1 = xrow0 + (size_t)32 * F_;

    // per-lane B pointers (swizzle baked into btK storage); wave covers 32 cols
    const int nA = n0 + w * 32 + fr;        // j = 0 column
    const int nB = nA + 16;                 // j = 1 column
    const _Float16* bp0 = btK + (size_t)nA * 32 + ((q ^ ((nA >> 1) & 3)) << 3);
    const _Float16* bp1 = btK + (size_t)nB * 32 + ((q ^ ((nB >> 1) & 3)) << 3);

    #define LOADB(t, bfv)                                                     \
    {                                                                         \
        bfv[0] = *reinterpret_cast<const f16x8*>(bp0 + (size_t)(t) * 16384);  \
        bfv[1] = *reinterpret_cast<const f16x8*>(bp1 + (size_t)(t) * 16384);  \
    }

    #define LOADX(t, va, vb)                                                  \
    {                                                                         \
        va = *reinterpret_cast<const float4*>(xrow0 + (size_t)(t) * 32);      \
        vb = *reinterpret_cast<const float4*>(xrow1 + (size_t)(t) * 32);      \
    }

    #define WRITE_A(va, vb, buf)                                              \
    {                                                                         \
        f16x4 h0; h0[0] = (_Float16)va.x; h0[1] = (_Float16)va.y;             \
        h0[2] = (_Float16)va.z; h0[3] = (_Float16)va.w;                       \
        f16x4 h1; h1[0] = (_Float16)vb.x; h1[1] = (_Float16)vb.y;             \
        h1[2] = (_Float16)vb.z; h1[3] = (_Float16)vb.w;                       \
        char* ab = reinterpret_cast<char*>(&As[buf][0]);                      \
        *reinterpret_cast<f16x4*>(ab + ar * 64 + abyte) = h0;                 \
        *reinterpret_cast<f16x4*>(ab + (ar + 32) * 64 + abyte) = h1;          \
    }

    #define COMPUTE(buf, bfv)                                                 \
    {                                                                         \
        f16x8 af[4];                                                          \
        _Pragma("unroll")                                                     \
        for (int i = 0; i < 4; ++i) {                                         \
            int r   = i * 16 + fr;                                            \
            int off = r * 64 + ((q ^ ((r >> 1) & 3)) << 4);                   \
            af[i] = *reinterpret_cast<const f16x8*>(                          \
                reinterpret_cast<const char*>(&As[buf][0]) + off);            \
        }                                                                     \
        _Pragma("unroll")                                                     \
        for (int i = 0; i < 4; ++i)                                           \
            _Pragma("unroll")                                                 \
            for (int j = 0; j < 2; ++j)                                       \
                acc[i][j] = __builtin_amdgcn_mfma_f32_16x16x32_f16(           \
                    af[i], bfv[j], acc[i][j], 0, 0, 0);                       \
    }

    f32x4 acc[4][2] = {};
    f16x8 bfA[2], bfB[2];
    float4 xa0, xa1, xb0, xb1;

    // prologue
    LOADX(0, xa0, xa1) LOADX(1, xb0, xb1)
    LOADB(0, bfA) LOADB(1, bfB)
    WRITE_A(xa0, xa1, 0)
    lds_barrier();

    for (int t = 0; t < 126; t += 2) {
        LOADX(t + 2, xa0, xa1)
        WRITE_A(xb0, xb1, 1)
        COMPUTE(0, bfA)
        LOADB(t + 2, bfA)
        lds_barrier();
        LOADX(t + 3, xb0, xb1)
        WRITE_A(xa0, xa1, 0)
        COMPUTE(1, bfB)
        LOADB(t + 3, bfB)
        lds_barrier();
    }
    WRITE_A(xb0, xb1, 1)
    COMPUTE(0, bfA)
    lds_barrier();
    COMPUTE(1, bfB)

    #undef LOADB
    #undef LOADX
    #undef WRITE_A
    #undef COMPUTE

    // planar z store: z[row][nn], nn = gate*128 + ch. Lanes fr-contiguous ->
    // 16 consecutive floats (64B) per quarter-wave store burst.
    #pragma unroll
    for (int j = 0; j < 2; ++j) {
        const int nn = n0 + w * 32 + j * 16 + fr;
        const float bj = bias[nn];
        #pragma unroll
        for (int i = 0; i < 4; ++i)
            #pragma unroll
            for (int r = 0; r < 4; ++r)
                z[(size_t)(m0 + i * 16 + q * 4 + r) * G4H + nn]
                    = acc[i][j][r] + bj;
    }
}

// ---------------------------------------------------------------------------
// Kernel 2: MFMA LSTM recurrence — R18 body (known 228us total, bit-exact),
// split into two 256-step dispatches via cst/h16 handoff (round-0's proven
// pattern) PURELY so gemm's counters enter the rocprof top-5.
// z is now PLANAR: gate g of channel jj at z[(b*T+t)*512 + g*128 + jj]
// (same values as before, different addresses; 4 scalar prefetch loads).
// ---------------------------------------------------------------------------
__device__ __forceinline__ float sig_f(float x) {
    return __builtin_amdgcn_rcpf(
        1.0f + __builtin_amdgcn_exp2f(-1.442695040888963f * x));
}
__device__ __forceinline__ float tanh_f(float x) {
    return 1.0f - 2.0f * __builtin_amdgcn_rcpf(
        1.0f + __builtin_amdgcn_exp2f(2.885390081777927f * x));
}

__global__ __launch_bounds__(512, 2) void lstm_mfma(
    const float* __restrict__ z,       // [B*T, 512] planar
    const _Float16* __restrict__ wrT,  // [4H, H] = Wr^T fp16
    float* __restrict__ hs,            // [B, T, H] fp32
    float* __restrict__ cst,           // [B, H] c-state handoff
    _Float16* __restrict__ h16,        // [B, H] h handoff (bit-exact fp16)
    int t0)                            // 0 or 256
{
    const int b    = blockIdx.x;
    const int tid  = threadIdx.x;
    const int w    = tid >> 6;
    const int lane = tid & 63;
    const int l15  = lane & 15;
    const int q    = lane >> 4;
    const int jj   = w * 16 + l15;

    __shared__ __align__(16) _Float16 hA[2][128];

    f16x8 bf[4][4];
    #pragma unroll
    for (int g = 0; g < 4; ++g)
        #pragma unroll
        for (int kf = 0; kf < 4; ++kf)
            bf[g][kf] = *reinterpret_cast<const f16x8*>(
                &wrT[(size_t)(g * H_ + jj) * H_ + kf * 32 + q * 8]);

    float cstate;
    if (t0 == 0) {
        if (tid < 128) reinterpret_cast<unsigned int*>(hA)[tid] = 0u;
        cstate = 0.f;
    } else {
        if (tid < 64)
            reinterpret_cast<unsigned int*>(hA[0])[tid] =
                reinterpret_cast<const unsigned int*>(h16 + (size_t)b * H_)[tid];
        cstate = cst[(size_t)b * H_ + jj];
    }

    const float* zq    = z  + (size_t)b * T_ * G4H + jj;   // + t*512 + g*128
    float*       hbase = hs + (size_t)b * T_ * H_;

    const f32x4 zero4 = {0.f, 0.f, 0.f, 0.f};

    #define LOADZ(t, d)                                                       \
    {                                                                         \
        int zo = (((t) & (T_ - 1)) << 9);                                     \
        d.x = zq[zo];       d.y = zq[zo + 128];                               \
        d.z = zq[zo + 256]; d.w = zq[zo + 384];                               \
    }

    float4 zP0, zP1, zP2, zP3;
    LOADZ(t0 + 0, zP0) LOADZ(t0 + 1, zP1)
    LOADZ(t0 + 2, zP2) LOADZ(t0 + 3, zP3)

    __syncthreads();

    #define LSTM_STEP(t, CUR, ZZ)                                             \
    {                                                                         \
        f16x8 af0 = *reinterpret_cast<const f16x8*>(&hA[CUR][0 * 32 + q * 8]);\
        f16x8 af1 = *reinterpret_cast<const f16x8*>(&hA[CUR][1 * 32 + q * 8]);\
        f16x8 af2 = *reinterpret_cast<const f16x8*>(&hA[CUR][2 * 32 + q * 8]);\
        f16x8 af3 = *reinterpret_cast<const f16x8*>(&hA[CUR][3 * 32 + q * 8]);\
        float zt0_ = ZZ.x, zt1_ = ZZ.y, zt2_ = ZZ.z, zt3_ = ZZ.w;             \
        LOADZ((t) + 4, ZZ)                                                    \
        float gv[4];                                                          \
        _Pragma("unroll")                                                     \
        for (int g = 0; g < 4; ++g) {                                         \
            f32x4 aA = __builtin_amdgcn_mfma_f32_16x16x32_f16(                \
                af0, bf[g][0], zero4, 0, 0, 0);                               \
            aA = __builtin_amdgcn_mfma_f32_16x16x32_f16(                      \
                af1, bf[g][1], aA, 0, 0, 0);                                  \
            f32x4 aB = __builtin_amdgcn_mfma_f32_16x16x32_f16(                \
                af2, bf[g][2], zero4, 0, 0, 0);                               \
            aB = __builtin_amdgcn_mfma_f32_16x16x32_f16(                      \
                af3, bf[g][3], aB, 0, 0, 0);                                  \
            gv[g] = aA[0] + aB[0];                                            \
        }                                                                     \
        float iv = sig_f(gv[0] + zt0_);                                       \
        float fv = sig_f(gv[1] + zt1_);                                       \
        float cc = tanh_f(gv[2] + zt2_);                                      \
        float ov = sig_f(gv[3] + zt3_);                                       \
        cstate = fv * cstate + iv * cc;                                       \
        float h = ov * tanh_f(cstate);                                        \
        if (q == 0) {                                                         \
            hA[CUR ^ 1][jj] = (_Float16)h;                                    \
            hbase[((t) << 7) + jj] = h;                                       \
        }                                                                     \
        lds_barrier();                                                        \
    }

    for (int t = t0; t < t0 + 256; t += 4) {
        LSTM_STEP(t,     0, zP0)
        LSTM_STEP(t + 1, 1, zP1)
        LSTM_STEP(t + 2, 0, zP2)
        LSTM_STEP(t + 3, 1, zP3)
    }
    #undef LSTM_STEP
    #undef LOADZ

    // handoff (last step wrote hA[0]; hA visible after its lds_barrier)
    if (q == 0) cst[(size_t)b * H_ + jj] = cstate;
    if (tid < 64)
        reinterpret_cast<unsigned int*>(h16 + (size_t)b * H_)[tid] =
            reinterpret_cast<unsigned int*>(hA[0])[tid];
}

// ---------------------------------------------------------------------------
// Kernel 3: out = hs @ Wd + bd
// ---------------------------------------------------------------------------
__global__ __launch_bounds__(256) void dense_out(
    const float* __restrict__ hs, const float* __restrict__ Wd,
    const float* __restrict__ bd, float* __restrict__ out)
{
    int idx = blockIdx.x * 256 + threadIdx.x;
    if (idx >= B_ * T_ * NCLS) return;
    int cls = idx % NCLS;
    int row = idx / NCLS;
    const float* h = hs + (size_t)row * H_;
    float acc = bd[cls];
    #pragma unroll 8
    for (int k = 0; k < H_; ++k) acc += h[k] * Wd[k * NCLS + cls];
    out[idx] = acc;
}

// ---------------------------------------------------------------------------
extern "C" void kernel_launch(void* const* d_in, const int* in_sizes, int n_in,
                              void* d_out, int out_size, void* d_ws, size_t ws_size,
                              hipStream_t stream)
{
    const float* x  = (const float*)d_in[0];
    const float* Wk = (const float*)d_in[1];
    const float* Wr = (const float*)d_in[2];
    const float* b  = (const float*)d_in[3];
    const float* Wd = (const float*)d_in[4];
    const float* bd = (const float*)d_in[5];
    float* out = (float*)d_out;

    float*     z   = (float*)d_ws;                       // [M, 512] fp32 planar
    float*     hs  = z + (size_t)M_ * G4H;               // [M, H]  fp32
    _Float16*  btK = (_Float16*)(hs + (size_t)M_ * H_);  // k-major swizzled, 4 MB
    _Float16*  wrT = btK + (size_t)G4H * F_;             // [4H, H] fp16
    float*     cst = (float*)(wrT + (size_t)G4H * H_);   // [B, H] fp32
    _Float16*  h16 = (_Float16*)(cst + (size_t)B_ * H_); // [B, H] fp16

    cvt_wkT<<<dim3(F_ / 64, G4H / 64), 256, 0, stream>>>(Wk, btK);
    cvt_wrT<<<dim3(H_ / 64, G4H / 64), 256, 0, stream>>>(Wr, wrT);
    gemm_fused<<<1024, 256, 0, stream>>>(x, btK, b, z);
    lstm_mfma<<<B_, 512, 0, stream>>>(z, wrT, hs, cst, h16, 0);
    lstm_mfma<<<B_, 512, 0, stream>>>(z, wrT, hs, cst, h16, 256);
    int total = B_ * T_ * NCLS;
    dense_out<<<(total + 255) / 256, 256, 0, stream>>>(hs, Wd, bd, out);
}

// Round 8
// 357.492 us; speedup vs baseline: 1.2146x; 1.2146x over previous
//
#include <hip/hip_runtime.h>
#include <hip/hip_bf16.h>
#include <hip/hip_fp16.h>
#include <math.h>

// Problem dims (fixed by reference)
#define B_  32
#define T_  512
#define F_  4096
#define H_  128
#define G4H 512           // 4*H
#define NCLS 3            // NUM_CLASSES + 1
#define M_  (B_ * T_)     // 16384 rows
#define KSTEPS 128        // F_/32

typedef _Float16 f16x8 __attribute__((ext_vector_type(8)));
typedef _Float16 f16x4 __attribute__((ext_vector_type(4)));
typedef float    f32x4 __attribute__((ext_vector_type(4)));

// ---------------------------------------------------------------------------
// Kernel 0b: Wk [F,4H] fp32 -> btK fp16, K-MAJOR tiles with baked-in group
// swizzle: group g (8 halves) of column n stored at half-offset
//   n*32 + ((g ^ ((n>>1)&3)) << 3)
// ---------------------------------------------------------------------------
__global__ __launch_bounds__(256) void cvt_wkT(
    const float* __restrict__ Wk, _Float16* __restrict__ btK)
{
    __shared__ float ls[64][65];
    const int k0 = blockIdx.x * 64;
    const int n0 = blockIdx.y * 64;
    const int tid = threadIdx.x;

    {
        int r  = tid >> 4;
        int c4 = (tid & 15) * 4;
        #pragma unroll
        for (int p = 0; p < 4; ++p) {
            float4 v = *reinterpret_cast<const float4*>(
                &Wk[(size_t)(k0 + r + p * 16) * G4H + n0 + c4]);
            ls[r + p * 16][c4 + 0] = v.x;
            ls[r + p * 16][c4 + 1] = v.y;
            ls[r + p * 16][c4 + 2] = v.z;
            ls[r + p * 16][c4 + 3] = v.w;
        }
    }
    __syncthreads();
    {
        int rn = tid >> 2;            // n within tile 0..63
        int ck = (tid & 3) * 16;      // k within tile 0,16,32,48
        f16x8 h0, h1;
        #pragma unroll
        for (int j = 0; j < 8; ++j) {
            h0[j] = (_Float16)ls[ck + j][rn];
            h1[j] = (_Float16)ls[ck + 8 + j][rn];
        }
        const int n    = n0 + rn;
        const int kg   = k0 + ck;
        const int kblk = kg >> 5;
        const int kk   = kg & 31;           // 0 or 16
        const int g0   = kk >> 3;           // 0 or 2
        const int sw   = (n >> 1) & 3;
        _Float16* base = btK + (size_t)kblk * (512 * 32) + (size_t)n * 32;
        *reinterpret_cast<f16x8*>(base + ((g0 ^ sw) << 3))       = h0;
        *reinterpret_cast<f16x8*>(base + (((g0 + 1) ^ sw) << 3)) = h1;
    }
}

// ---------------------------------------------------------------------------
// Kernel 0c: Wr [H,4H] fp32 -> wrT [4H,H] fp16 (transpose). grid (2, 8).
// ---------------------------------------------------------------------------
__global__ __launch_bounds__(256) void cvt_wrT(
    const float* __restrict__ Wr, _Float16* __restrict__ wrT)
{
    __shared__ float ls[64][65];
    const int k0 = blockIdx.x * 64;
    const int n0 = blockIdx.y * 64;
    const int tid = threadIdx.x;
    {
        int r  = tid >> 4;
        int c4 = (tid & 15) * 4;
        #pragma unroll
        for (int p = 0; p < 4; ++p) {
            float4 v = *reinterpret_cast<const float4*>(
                &Wr[(size_t)(k0 + r + p * 16) * G4H + n0 + c4]);
            ls[r + p * 16][c4 + 0] = v.x;
            ls[r + p * 16][c4 + 1] = v.y;
            ls[r + p * 16][c4 + 2] = v.z;
            ls[r + p * 16][c4 + 3] = v.w;
        }
    }
    __syncthreads();
    {
        int rn = tid >> 2;
        int ck = (tid & 3) * 16;
        f16x8 h0, h1;
        #pragma unroll
        for (int j = 0; j < 8; ++j) {
            h0[j] = (_Float16)ls[ck + j][rn];
            h1[j] = (_Float16)ls[ck + 8 + j][rn];
        }
        _Float16* dst = &wrT[(size_t)(n0 + rn) * H_ + k0 + ck];
        *reinterpret_cast<f16x8*>(dst)     = h0;
        *reinterpret_cast<f16x8*>(dst + 8) = h1;
    }
}

// Light producer-consumer barrier: LDS-drain only, no vmcnt drain.
__device__ __forceinline__ void lds_barrier() {
    asm volatile("s_waitcnt lgkmcnt(0)" ::: "memory");
    __builtin_amdgcn_s_barrier();
    asm volatile("" ::: "memory");
}

// ---------------------------------------------------------------------------
// Kernel 1: FUSED z = f16(x) @ Wk + b.
// R23: R21 base (8 waves, BN=256, B-in-regs, 2 blk/CU — best known ~139us)
// with ONE change: 4 K-steps of A staged per barrier (As[2][4] ping-pong,
// 32KB LDS). Barrier count 128 -> 34. Theory: per-step barrier convoy is the
// cost (R22 showed all pipes idle at 43% occupancy). x loaded one group
// ahead (>=4-step lead, HBM covered); B 2-deep reg ping-pong (L2 lead).
// Same k-order / RTN cvt / fragments => z bit-exact. z stored PLANAR
// (R22's layout — lstm improved with it).
// ---------------------------------------------------------------------------
__global__ __launch_bounds__(512, 4) void gemm_fused(
    const float* __restrict__ x, const _Float16* __restrict__ btK,
    const float* __restrict__ bias, float* __restrict__ z)
{
    __shared__ __align__(16) _Float16 As[2][4][64 * 32];   // 32 KB

    const int tid = threadIdx.x;
    const int w   = tid >> 6;
    const int l   = tid & 63;
    const int fr  = l & 15;
    const int q   = l >> 4;

    // 512 blocks = 8 xcd * (32 m-pairs * 2 n); siblings adjacent on one XCD
    const int bid   = blockIdx.x;
    const int xcd   = bid & 7;
    const int idx   = bid >> 3;
    const int mt    = xcd * 32 + (idx >> 1);
    const int ntile = idx & 1;
    const int m0    = mt * 64;
    const int n0    = ntile * 256;

    // x staging: thread -> (row ar, cols hc..hc+3), swizzled f16 LDS layout
    const int ar = tid >> 3;
    const int hc = (tid & 7) * 4;
    const int abyte = ((((hc >> 3) ^ ((ar >> 1) & 3)) << 4) | ((hc << 1) & 15));
    const float* xrow = x + (size_t)(m0 + ar) * F_ + hc;

    // per-lane B pointers (swizzle baked into btK storage)
    const int nA = n0 + w * 32 + fr;        // j = 0 column
    const int nB = nA + 16;                 // j = 1 column
    const _Float16* bp0 = btK + (size_t)nA * 32 + ((q ^ ((nA >> 1) & 3)) << 3);
    const _Float16* bp1 = btK + (size_t)nB * 32 + ((q ^ ((nB >> 1) & 3)) << 3);

    #define LOADB(t, bfv)                                                     \
    {                                                                         \
        bfv[0] = *reinterpret_cast<const f16x8*>(bp0 + (size_t)(t) * 16384);  \
        bfv[1] = *reinterpret_cast<const f16x8*>(bp1 + (size_t)(t) * 16384);  \
    }

    #define LOADX(t) (*reinterpret_cast<const float4*>(xrow + (size_t)(t) * 32))

    #define WRITE_A(v, G, s)                                                  \
    {                                                                         \
        f16x4 hh; hh[0] = (_Float16)v.x; hh[1] = (_Float16)v.y;               \
        hh[2] = (_Float16)v.z; hh[3] = (_Float16)v.w;                         \
        *reinterpret_cast<f16x4*>(                                            \
            reinterpret_cast<char*>(&As[G][s][0]) + ar * 64 + abyte) = hh;    \
    }

    #define COMPUTE(G, s, bfv)                                                \
    {                                                                         \
        f16x8 af[4];                                                          \
        _Pragma("unroll")                                                     \
        for (int i = 0; i < 4; ++i) {                                         \
            int r   = i * 16 + fr;                                            \
            int off = r * 64 + ((q ^ ((r >> 1) & 3)) << 4);                   \
            af[i] = *reinterpret_cast<const f16x8*>(                          \
                reinterpret_cast<const char*>(&As[G][s][0]) + off);           \
        }                                                                     \
        _Pragma("unroll")                                                     \
        for (int i = 0; i < 4; ++i)                                           \
            _Pragma("unroll")                                                 \
            for (int j = 0; j < 2; ++j)                                       \
                acc[i][j] = __builtin_amdgcn_mfma_f32_16x16x32_f16(           \
                    af[i], bfv[j], acc[i][j], 0, 0, 0);                       \
    }

    // One group = 4 K-steps computed from As[G], staging group g+1 into
    // As[G^1], issuing x for group g+2. One barrier per group.
    #define GROUP(t0, G)                                                      \
    {                                                                         \
        WRITE_A(xq0, G ^ 1, 0) WRITE_A(xq1, G ^ 1, 1)                         \
        WRITE_A(xq2, G ^ 1, 2) WRITE_A(xq3, G ^ 1, 3)                         \
        xq0 = LOADX((t0) + 8);  xq1 = LOADX((t0) + 9);                        \
        xq2 = LOADX((t0) + 10); xq3 = LOADX((t0) + 11);                       \
        COMPUTE(G, 0, bfA) LOADB((t0) + 2, bfA)                               \
        COMPUTE(G, 1, bfB) LOADB((t0) + 3, bfB)                               \
        COMPUTE(G, 2, bfA) LOADB((t0) + 4, bfA)                               \
        COMPUTE(G, 3, bfB) LOADB((t0) + 5, bfB)                               \
        lds_barrier();                                                        \
    }

    f32x4 acc[4][2] = {};
    f16x8 bfA[2], bfB[2];
    float4 xq0, xq1, xq2, xq3;

    // prologue: stage group 0, preload x for group 1, B(0),B(1)
    xq0 = LOADX(0); xq1 = LOADX(1); xq2 = LOADX(2); xq3 = LOADX(3);
    WRITE_A(xq0, 0, 0) WRITE_A(xq1, 0, 1) WRITE_A(xq2, 0, 2) WRITE_A(xq3, 0, 3)
    xq0 = LOADX(4); xq1 = LOADX(5); xq2 = LOADX(6); xq3 = LOADX(7);
    LOADB(0, bfA) LOADB(1, bfB)
    lds_barrier();

    // groups 0..29 (t0 = 0..116): full steady state (x issue reaches t=127)
    for (int gg = 0; gg < 30; gg += 2) {
        const int t0 = gg * 4;
        GROUP(t0, 0)
        GROUP(t0 + 4, 1)
    }
    // group 30 (t0=120, G=0): stage group 31, no more x issue
    {
        WRITE_A(xq0, 1, 0) WRITE_A(xq1, 1, 1) WRITE_A(xq2, 1, 2) WRITE_A(xq3, 1, 3)
        COMPUTE(0, 0, bfA) LOADB(122, bfA)
        COMPUTE(0, 1, bfB) LOADB(123, bfB)
        COMPUTE(0, 2, bfA) LOADB(124, bfA)
        COMPUTE(0, 3, bfB) LOADB(125, bfB)
        lds_barrier();
    }
    // group 31 (t0=124, G=1): final
    {
        COMPUTE(1, 0, bfA) LOADB(126, bfA)
        COMPUTE(1, 1, bfB) LOADB(127, bfB)
        COMPUTE(1, 2, bfA)
        COMPUTE(1, 3, bfB)
    }

    #undef LOADB
    #undef LOADX
    #undef WRITE_A
    #undef COMPUTE
    #undef GROUP

    // planar z store: z[row][nn] (gate = nn>>7, ch = nn&127)
    #pragma unroll
    for (int j = 0; j < 2; ++j) {
        const int nn = n0 + w * 32 + j * 16 + fr;
        const float bj = bias[nn];
        #pragma unroll
        for (int i = 0; i < 4; ++i)
            #pragma unroll
            for (int r = 0; r < 4; ++r)
                z[(size_t)(m0 + i * 16 + q * 4 + r) * G4H + nn]
                    = acc[i][j][r] + bj;
    }
}

// ---------------------------------------------------------------------------
// Kernel 2: MFMA LSTM recurrence — EXACT R22 body (two 256-step halves,
// planar z reads, ~97us/half, bit-exact).
// ---------------------------------------------------------------------------
__device__ __forceinline__ float sig_f(float x) {
    return __builtin_amdgcn_rcpf(
        1.0f + __builtin_amdgcn_exp2f(-1.442695040888963f * x));
}
__device__ __forceinline__ float tanh_f(float x) {
    return 1.0f - 2.0f * __builtin_amdgcn_rcpf(
        1.0f + __builtin_amdgcn_exp2f(2.885390081777927f * x));
}

__global__ __launch_bounds__(512, 2) void lstm_mfma(
    const float* __restrict__ z,       // [B*T, 512] planar
    const _Float16* __restrict__ wrT,  // [4H, H] = Wr^T fp16
    float* __restrict__ hs,            // [B, T, H] fp32
    float* __restrict__ cst,           // [B, H] c-state handoff
    _Float16* __restrict__ h16,        // [B, H] h handoff (bit-exact fp16)
    int t0)                            // 0 or 256
{
    const int b    = blockIdx.x;
    const int tid  = threadIdx.x;
    const int w    = tid >> 6;
    const int lane = tid & 63;
    const int l15  = lane & 15;
    const int q    = lane >> 4;
    const int jj   = w * 16 + l15;

    __shared__ __align__(16) _Float16 hA[2][128];

    f16x8 bf[4][4];
    #pragma unroll
    for (int g = 0; g < 4; ++g)
        #pragma unroll
        for (int kf = 0; kf < 4; ++kf)
            bf[g][kf] = *reinterpret_cast<const f16x8*>(
                &wrT[(size_t)(g * H_ + jj) * H_ + kf * 32 + q * 8]);

    float cstate;
    if (t0 == 0) {
        if (tid < 128) reinterpret_cast<unsigned int*>(hA)[tid] = 0u;
        cstate = 0.f;
    } else {
        if (tid < 64)
            reinterpret_cast<unsigned int*>(hA[0])[tid] =
                reinterpret_cast<const unsigned int*>(h16 + (size_t)b * H_)[tid];
        cstate = cst[(size_t)b * H_ + jj];
    }

    const float* zq    = z  + (size_t)b * T_ * G4H + jj;   // + t*512 + g*128
    float*       hbase = hs + (size_t)b * T_ * H_;

    const f32x4 zero4 = {0.f, 0.f, 0.f, 0.f};

    #define LOADZ(t, d)                                                       \
    {                                                                         \
        int zo = (((t) & (T_ - 1)) << 9);                                     \
        d.x = zq[zo];       d.y = zq[zo + 128];                               \
        d.z = zq[zo + 256]; d.w = zq[zo + 384];                               \
    }

    float4 zP0, zP1, zP2, zP3;
    LOADZ(t0 + 0, zP0) LOADZ(t0 + 1, zP1)
    LOADZ(t0 + 2, zP2) LOADZ(t0 + 3, zP3)

    __syncthreads();

    #define LSTM_STEP(t, CUR, ZZ)                                             \
    {                                                                         \
        f16x8 af0 = *reinterpret_cast<const f16x8*>(&hA[CUR][0 * 32 + q * 8]);\
        f16x8 af1 = *reinterpret_cast<const f16x8*>(&hA[CUR][1 * 32 + q * 8]);\
        f16x8 af2 = *reinterpret_cast<const f16x8*>(&hA[CUR][2 * 32 + q * 8]);\
        f16x8 af3 = *reinterpret_cast<const f16x8*>(&hA[CUR][3 * 32 + q * 8]);\
        float zt0_ = ZZ.x, zt1_ = ZZ.y, zt2_ = ZZ.z, zt3_ = ZZ.w;             \
        LOADZ((t) + 4, ZZ)                                                    \
        float gv[4];                                                          \
        _Pragma("unroll")                                                     \
        for (int g = 0; g < 4; ++g) {                                         \
            f32x4 aA = __builtin_amdgcn_mfma_f32_16x16x32_f16(                \
                af0, bf[g][0], zero4, 0, 0, 0);                               \
            aA = __builtin_amdgcn_mfma_f32_16x16x32_f16(                      \
                af1, bf[g][1], aA, 0, 0, 0);                                  \
            f32x4 aB = __builtin_amdgcn_mfma_f32_16x16x32_f16(                \
                af2, bf[g][2], zero4, 0, 0, 0);                               \
            aB = __builtin_amdgcn_mfma_f32_16x16x32_f16(                      \
                af3, bf[g][3], aB, 0, 0, 0);                                  \
            gv[g] = aA[0] + aB[0];                                            \
        }                                                                     \
        float iv = sig_f(gv[0] + zt0_);                                       \
        float fv = sig_f(gv[1] + zt1_);                                       \
        float cc = tanh_f(gv[2] + zt2_);                                      \
        float ov = sig_f(gv[3] + zt3_);                                       \
        cstate = fv * cstate + iv * cc;                                       \
        float h = ov * tanh_f(cstate);                                        \
        if (q == 0) {                                                         \
            hA[CUR ^ 1][jj] = (_Float16)h;                                    \
            hbase[((t) << 7) + jj] = h;                                       \
        }                                                                     \
        lds_barrier();                                                        \
    }

    for (int t = t0; t < t0 + 256; t += 4) {
        LSTM_STEP(t,     0, zP0)
        LSTM_STEP(t + 1, 1, zP1)
        LSTM_STEP(t + 2, 0, zP2)
        LSTM_STEP(t + 3, 1, zP3)
    }
    #undef LSTM_STEP
    #undef LOADZ

    // handoff (last step wrote hA[0]; hA visible after its lds_barrier)
    if (q == 0) cst[(size_t)b * H_ + jj] = cstate;
    if (tid < 64)
        reinterpret_cast<unsigned int*>(h16 + (size_t)b * H_)[tid] =
            reinterpret_cast<unsigned int*>(hA[0])[tid];
}

// ---------------------------------------------------------------------------
// Kernel 3: out = hs @ Wd + bd
// ---------------------------------------------------------------------------
__global__ __launch_bounds__(256) void dense_out(
    const float* __restrict__ hs, const float* __restrict__ Wd,
    const float* __restrict__ bd, float* __restrict__ out)
{
    int idx = blockIdx.x * 256 + threadIdx.x;
    if (idx >= B_ * T_ * NCLS) return;
    int cls = idx % NCLS;
    int row = idx / NCLS;
    const float* h = hs + (size_t)row * H_;
    float acc = bd[cls];
    #pragma unroll 8
    for (int k = 0; k < H_; ++k) acc += h[k] * Wd[k * NCLS + cls];
    out[idx] = acc;
}

// ---------------------------------------------------------------------------
extern "C" void kernel_launch(void* const* d_in, const int* in_sizes, int n_in,
                              void* d_out, int out_size, void* d_ws, size_t ws_size,
                              hipStream_t stream)
{
    const float* x  = (const float*)d_in[0];
    const float* Wk = (const float*)d_in[1];
    const float* Wr = (const float*)d_in[2];
    const float* b  = (const float*)d_in[3];
    const float* Wd = (const float*)d_in[4];
    const float* bd = (const float*)d_in[5];
    float* out = (float*)d_out;

    float*     z   = (float*)d_ws;                       // [M, 512] fp32 planar
    float*     hs  = z + (size_t)M_ * G4H;               // [M, H]  fp32
    _Float16*  btK = (_Float16*)(hs + (size_t)M_ * H_);  // k-major swizzled, 4 MB
    _Float16*  wrT = btK + (size_t)G4H * F_;             // [4H, H] fp16
    float*     cst = (float*)(wrT + (size_t)G4H * H_);   // [B, H] fp32
    _Float16*  h16 = (_Float16*)(cst + (size_t)B_ * H_); // [B, H] fp16

    cvt_wkT<<<dim3(F_ / 64, G4H / 64), 256, 0, stream>>>(Wk, btK);
    cvt_wrT<<<dim3(H_ / 64, G4H / 64), 256, 0, stream>>>(Wr, wrT);
    gemm_fused<<<512, 512, 0, stream>>>(x, btK, b, z);
    lstm_mfma<<<B_, 512, 0, stream>>>(z, wrT, hs, cst, h16, 0);
    lstm_mfma<<<B_, 512, 0, stream>>>(z, wrT, hs, cst, h16, 256);
    int total = B_ * T_ * NCLS;
    dense_out<<<(total + 255) / 256, 256, 0, stream>>>(hs, Wd, bd, out);
}